// Round 7
// baseline (232.019 us; speedup 1.0000x reference)
//
#include <hip/hip_runtime.h>

// ---------------------------------------------------------------------------
// AttentionFuse: out[b,d] = mean_s( softmax((x Wq + bq)(x Wk + bk)^T / 32) @ (x Wv + bv) )
// Algebra:
//   mean_s(attn @ V) = sum_t a[t] * V[t,:],  a[t] = (1/S) sum_s attn[s,t]
//   => out = (a^T x) Wv + bv   (V GEMM eliminated).
//   q.k = q0.k0 + (row-const: DROP) + bq.k0 + (bq.bk row-const: DROP)
//   => P[s,t] = exp(scale*q0.k0 + c[t]),  c[t] = scale*(k0[t].bq)  [fused into k_proj]
// GEMM core R7: m201-exact sync discipline — builtin s_barrier (NO memory
//   clobber), clobber-free s_waitcnt, reads issued pre-bar1, 16-MFMA cluster
//   between bar1/bar2, lgkmcnt(8) on 12-read phases, counted vmcnt(4) at
//   phases 4/8. R4-R6 all stalled at 33% MfmaUtil; the one shared element was
//   asm ":::memory" clobbers forcing compiler-inserted full drains per phase.
// ---------------------------------------------------------------------------

using bf16x8 = __attribute__((ext_vector_type(8))) __bf16;
using u16x8  = __attribute__((ext_vector_type(8))) unsigned short;
using f32x4  = __attribute__((ext_vector_type(4))) float;

#define NB 8
#define SEQ 2048
#define DIM 1024
#define MTOT (NB * SEQ)          // 16384
static const size_t QKV_STRIDE = (size_t)MTOT * DIM;

__device__ __forceinline__ unsigned short f2bf(float f) {
    unsigned int u = __float_as_uint(f);
    u = u + 0x7FFFu + ((u >> 16) & 1u);   // round-to-nearest-even
    return (unsigned short)(u >> 16);
}
__device__ __forceinline__ float bf2f(unsigned short h) {
    return __uint_as_float(((unsigned int)h) << 16);
}

__device__ __forceinline__ void async16(const unsigned short* g, unsigned short* l) {
    __builtin_amdgcn_global_load_lds(
        (const __attribute__((address_space(1))) void*)g,
        (__attribute__((address_space(3))) void*)l, 16, 0, 0);
}

// ---------------- K1: x fp32 -> bf16 ----------------
__global__ __launch_bounds__(256) void k_cvt_x(const float* __restrict__ x,
                                               unsigned short* __restrict__ xb) {
    size_t i = ((size_t)blockIdx.x * 256 + threadIdx.x) * 4;
    float4 v = *reinterpret_cast<const float4*>(x + i);
    ushort4 o;
    o.x = f2bf(v.x); o.y = f2bf(v.y); o.z = f2bf(v.z); o.w = f2bf(v.w);
    *reinterpret_cast<ushort4*>(xb + i) = o;
}

// ---------------- K2: W [k][n] fp32 -> Wt [n][k] bf16 (Wq, Wk) ----------------
__global__ __launch_bounds__(256) void k_transpose_w(const float* __restrict__ W0,
                                                     const float* __restrict__ W1,
                                                     unsigned short* __restrict__ wt) {
    __shared__ float t[64][65];
    const float* W = (blockIdx.z == 0) ? W0 : W1;
    unsigned short* Wt = wt + (size_t)blockIdx.z * DIM * DIM;
    int k0 = blockIdx.x * 64, n0 = blockIdx.y * 64;
    int tc = threadIdx.x & 15, tr = threadIdx.x >> 4;
#pragma unroll
    for (int i = 0; i < 4; ++i) {
        int kr = i * 16 + tr;
        float4 v = *reinterpret_cast<const float4*>(W + (size_t)(k0 + kr) * DIM + n0 + tc * 4);
        t[kr][tc * 4 + 0] = v.x; t[kr][tc * 4 + 1] = v.y;
        t[kr][tc * 4 + 2] = v.z; t[kr][tc * 4 + 3] = v.w;
    }
    __syncthreads();
#pragma unroll
    for (int i = 0; i < 4; ++i) {
        int nr = i * 16 + tr;
        ushort4 o;
        o.x = f2bf(t[tc * 4 + 0][nr]); o.y = f2bf(t[tc * 4 + 1][nr]);
        o.z = f2bf(t[tc * 4 + 2][nr]); o.w = f2bf(t[tc * 4 + 3][nr]);
        *reinterpret_cast<ushort4*>(Wt + (size_t)(n0 + nr) * DIM + k0 + tc * 4) = o;
    }
}

// ---------------------------------------------------------------------------
// 256x256 GEMM core, K = 1024. A row-major [M][lda], Bt row-major [N][ldb].
// LDS (ushort offs): Abuf(d)=d*16384 (+half*8192); Bbuf(d)=32768+d*16384 (+half*8192).
// LDS[r][s16] = G[r][s16 ^ (r&7)] (16B slots); FRAG XORs back.
// 8 phases / 2 K-tiles; each phase:
//   [ds_reads (compiler-visible)] [1 half-tile stage] [opt lgkmcnt(8)]
//   s_barrier ; lgkmcnt(0) ; setprio(1) ; 16 MFMA ; setprio(0) ; [opt vmcnt(4)]
//   s_barrier
// vmcnt(4)@P4 drains prev-P7,P8 + P1,P2 = buf1.A+B complete for P5 reads;
// vmcnt(4)@P8 drains P3..P6 = buf0.A+B complete for next-P1 reads.
// WAR: each stage target's last reader drained by that wave's lgkmcnt(0)
// >=1 barrier before the stage issues.
// ---------------------------------------------------------------------------

#define STAGE(gbase, ld, dstoff)                                          \
    do {                                                                  \
        async16((gbase), ldsw + (dstoff));                                \
        async16((gbase) + 8 * (size_t)(ld), ldsw + (dstoff) + 512);       \
    } while (0)
#define STAGE_A(buf, half, kt) STAGE(gA + (size_t)((half) * 128) * lda + (kt) * 64, lda, (buf) * 16384 + (half) * 8192)
#define STAGE_B(buf, half, kt) STAGE(gB + (size_t)((half) * 128) * ldb + (kt) * 64, ldb, 32768 + (buf) * 16384 + (half) * 8192)

#define FRAG(base_us, row, colb) \
    (*(const bf16x8*)((const char*)(lds + (base_us)) + (row) * 128 + ((colb) ^ (((row) & 7) << 4))))

#define READ_A(dbuf, mh)                                                      \
    _Pragma("unroll") for (int m2 = 0; m2 < 4; ++m2) {                        \
        int arow = ((mh) * 4 + m2) * 16 + fr;                                 \
        _Pragma("unroll") for (int ks = 0; ks < 2; ++ks)                      \
            afc[(mh) * 4 + m2][ks] =                                          \
                FRAG((dbuf) * 16384 + wr * 8192, arow, ks * 64 + fg * 16);    \
    }
#define READ_B(dbuf, nh)                                                      \
    _Pragma("unroll") for (int n2 = 0; n2 < 2; ++n2) {                        \
        int brow = (wc & 1) * 64 + ((nh) * 2 + n2) * 16 + fr;                 \
        _Pragma("unroll") for (int ks = 0; ks < 2; ++ks)                      \
            bfc[nh][n2][ks] =                                                 \
                FRAG(32768 + (dbuf) * 16384 + (wc >> 1) * 8192, brow,         \
                     ks * 64 + fg * 16);                                      \
    }

#define VM4 asm volatile("s_waitcnt vmcnt(4)")
#define LG8 asm volatile("s_waitcnt lgkmcnt(8)")

#define PHASE(mh, nh, RD, STG, LGOPT, VMOPT)                                  \
    do {                                                                      \
        RD;                                                                   \
        STG;                                                                  \
        LGOPT;                                                                \
        __builtin_amdgcn_s_barrier();                                         \
        asm volatile("s_waitcnt lgkmcnt(0)");                                 \
        __builtin_amdgcn_s_setprio(1);                                        \
        _Pragma("unroll") for (int m2 = 0; m2 < 4; ++m2)                      \
        _Pragma("unroll") for (int n2 = 0; n2 < 2; ++n2)                      \
        _Pragma("unroll") for (int ks = 0; ks < 2; ++ks)                      \
            acc[(mh) * 4 + m2][(nh) * 2 + n2] =                               \
                __builtin_amdgcn_mfma_f32_16x16x32_bf16(                      \
                    afc[(mh) * 4 + m2][ks], bfc[nh][n2][ks],                  \
                    acc[(mh) * 4 + m2][(nh) * 2 + n2], 0, 0, 0);              \
        __builtin_amdgcn_s_setprio(0);                                        \
        VMOPT;                                                                \
        __builtin_amdgcn_s_barrier();                                         \
    } while (0)

__device__ __forceinline__ void gemm256(const unsigned short* __restrict__ A,
                                        const unsigned short* __restrict__ Bt,
                                        int lda, int ldb, int m0, int n0,
                                        unsigned short* lds, f32x4 (&acc)[8][4]) {
    constexpr int NKT = 1024 / 64;   // 16 K-tiles
    constexpr int NIT = NKT / 2;     // 8 iterations
    const int tid = threadIdx.x;
    const int w = tid >> 6, lane = tid & 63;
    const int wr = w >> 2, wc = w & 3;
    const int fr = lane & 15, fg = lane >> 4;
    const int r8 = lane >> 3, slot = (lane & 7) ^ r8;

    const unsigned short* gA = A + (size_t)(m0 + w * 16 + r8) * lda + slot * 8;
    const unsigned short* gB = Bt + (size_t)(n0 + w * 16 + r8) * ldb + slot * 8;
    unsigned short* ldsw = lds + w * 1024;

    bf16x8 afc[8][2];        // A frags: [0-3]=mh0, [4-7]=mh1
    bf16x8 bfc[2][2][2];     // B frags per nh

    // prologue: buf0 = tile0 complete + buf1.A = tile1; vmcnt(4) drains buf0
    STAGE_A(0, 0, 0); STAGE_A(0, 1, 0); STAGE_B(0, 0, 0); STAGE_B(0, 1, 0);
    STAGE_A(1, 0, 1); STAGE_A(1, 1, 1);
    VM4;
    __builtin_amdgcn_s_barrier();

    for (int it = 0; it < NIT; ++it) {
        const int t1 = 2 * it + 1;
        const int ka = (2 * it + 2) & (NKT - 1);   // wraps harmlessly on last iter
        const int kb = (2 * it + 3) & (NKT - 1);
        // buf0 = K-tile 2it
        PHASE(0, 0, READ_A(0, 0); READ_B(0, 0), STAGE_B(1, 0, t1), LG8, );
        PHASE(1, 0, READ_A(0, 1),               STAGE_B(1, 1, t1), ,    );
        PHASE(0, 1, READ_B(0, 1),               STAGE_A(0, 0, ka), ,    );
        PHASE(1, 1, ,                           STAGE_A(0, 1, ka), , VM4);
        // buf1 = K-tile 2it+1
        PHASE(0, 0, READ_A(1, 0); READ_B(1, 0), STAGE_B(0, 0, ka), LG8, );
        PHASE(1, 0, READ_A(1, 1),               STAGE_B(0, 1, ka), ,    );
        PHASE(0, 1, READ_B(1, 1),               STAGE_A(1, 0, kb), ,    );
        PHASE(1, 1, ,                           STAGE_A(1, 1, kb), , VM4);
    }
    asm volatile("s_waitcnt vmcnt(0) lgkmcnt(0)");
}

// ---------------- K3: Q/K projection: qkv[z] = x @ W[z] (bf16); z=1 also
//                  accumulates c[t] = scale * k0[t].bq  (softmax-shifted) ----
__global__ __launch_bounds__(512, 2) void k_proj(const unsigned short* __restrict__ xb,
                                                 const unsigned short* __restrict__ wt,
                                                 const float* __restrict__ bq,
                                                 unsigned short* __restrict__ qkv,
                                                 float* __restrict__ c) {
    __shared__ unsigned short lds[65536];   // 128 KiB
    // XCD swizzle: xcd = f&7 owns contiguous 8-m-panel chunk; n,z innermost
    const int f = blockIdx.x;
    const int m_hi = f & 7, j = f >> 3;
    const int n_t = j & 3, z = (j >> 2) & 1, m_lo = j >> 3;
    const int m0 = (m_hi * 8 + m_lo) * 256, n0 = n_t * 256;

    const unsigned short* Bt = wt + (size_t)z * DIM * DIM;
    unsigned short* out = qkv + (size_t)z * QKV_STRIDE;

    f32x4 acc[8][4] = {};
    gemm256(xb, Bt, DIM, DIM, m0, n0, lds, acc);

    const int tid = threadIdx.x, w = tid >> 6, lane = tid & 63;
    const int wr = w >> 2, wc = w & 3, fr = lane & 15, fg = lane >> 4;
#pragma unroll
    for (int nf = 0; nf < 4; ++nf) {
        int n = n0 + wc * 64 + nf * 16 + fr;
#pragma unroll
        for (int mf = 0; mf < 8; ++mf) {
            int r0 = m0 + wr * 128 + mf * 16 + fg * 4;
#pragma unroll
            for (int j2 = 0; j2 < 4; ++j2)
                out[(size_t)(r0 + j2) * DIM + n] = f2bf(acc[mf][nf][j2]);
        }
    }
    if (z == 1) {
        // c[row] += scale * sum_n bq[n] * k0[row, n]  over this block's n-chunk
        float bqv[4];
#pragma unroll
        for (int nf = 0; nf < 4; ++nf) bqv[nf] = bq[n0 + wc * 64 + nf * 16 + fr];
#pragma unroll
        for (int mf = 0; mf < 8; ++mf) {
#pragma unroll
            for (int j2 = 0; j2 < 4; ++j2) {
                float s = 0.f;
#pragma unroll
                for (int nf = 0; nf < 4; ++nf) s += bqv[nf] * acc[mf][nf][j2];
                s += __shfl_xor(s, 1);
                s += __shfl_xor(s, 2);
                s += __shfl_xor(s, 4);
                s += __shfl_xor(s, 8);
                if (fr == 0)
                    atomicAdd(&c[m0 + wr * 128 + mf * 16 + fg * 4 + j2], 0.03125f * s);
            }
        }
    }
}

// ---------------- K4: P = exp(q0 k0^T * scale + c[t]) bf16, ell = rowsum ----------------
__global__ __launch_bounds__(512, 2) void k_scores(const unsigned short* __restrict__ qkv,
                                                   const float* __restrict__ c,
                                                   unsigned short* __restrict__ P,
                                                   float* __restrict__ ell) {
    __shared__ unsigned short lds[65536];
    // XCD swizzle: batch b -> xcd b; within batch k-panel (nt) held hot
    const int f = blockIdx.x;
    const int b = f & 7, j = f >> 3;
    const int mt = j & 7, nt = j >> 3;
    const unsigned short* q = qkv + (size_t)b * SEQ * DIM;
    const unsigned short* k = qkv + QKV_STRIDE + (size_t)b * SEQ * DIM;
    const int m0 = mt * 256, n0 = nt * 256;

    f32x4 acc[8][4] = {};
    gemm256(q, k, DIM, DIM, m0, n0, lds, acc);

    const float scale = 0.03125f;  // 1/sqrt(1024)
    const int tid = threadIdx.x, w = tid >> 6, lane = tid & 63;
    const int wr = w >> 2, wc = w & 3, fr = lane & 15, fg = lane >> 4;
    unsigned short* Pb = P + (size_t)b * SEQ * SEQ;
    float cv[4];
#pragma unroll
    for (int nf = 0; nf < 4; ++nf)
        cv[nf] = c[(size_t)b * SEQ + n0 + wc * 64 + nf * 16 + fr];
#pragma unroll
    for (int mf = 0; mf < 8; ++mf) {
#pragma unroll
        for (int j2 = 0; j2 < 4; ++j2) {
            int s = m0 + wr * 128 + mf * 16 + fg * 4 + j2;
            float rs = 0.f;
#pragma unroll
            for (int nf = 0; nf < 4; ++nf) {
                int t = n0 + wc * 64 + nf * 16 + fr;
                float p = __expf(acc[mf][nf][j2] * scale + cv[nf]);
                unsigned short pu = f2bf(p);
                Pb[(size_t)s * SEQ + t] = pu;
                rs += bf2f(pu);  // keep ell consistent with stored bf16 P
            }
            rs += __shfl_xor(rs, 1);
            rs += __shfl_xor(rs, 2);
            rs += __shfl_xor(rs, 4);
            rs += __shfl_xor(rs, 8);
            if (fr == 0) atomicAdd(&ell[b * SEQ + s], rs);
        }
    }
}

// ---------------- K5: ell -> 1/ell ----------------
__global__ __launch_bounds__(256) void k_recip(float* __restrict__ e) {
    int i = blockIdx.x * 256 + threadIdx.x;
    e[i] = 1.0f / e[i];
}

// ---------------- K6: w[b,t] = sum_s P[b,s,t] * rell[b,s]  (2 cols/thread) ----------------
__global__ __launch_bounds__(256) void k_colsum(const unsigned short* __restrict__ P,
                                                const float* __restrict__ rell,
                                                float* __restrict__ w) {
    int b = blockIdx.z;
    int t2 = (blockIdx.x * 256 + threadIdx.x) * 2;
    int s0 = blockIdx.y * 256;
    const unsigned short* Pb = P + (size_t)b * SEQ * SEQ;
    const float* eb = rell + b * SEQ;
    float a0 = 0.f, a1 = 0.f;
    for (int s = s0; s < s0 + 256; ++s) {
        ushort2 pv = *reinterpret_cast<const ushort2*>(Pb + (size_t)s * SEQ + t2);
        float e = eb[s];
        a0 += bf2f(pv.x) * e;
        a1 += bf2f(pv.y) * e;
    }
    atomicAdd(&w[b * SEQ + t2], a0);
    atomicAdd(&w[b * SEQ + t2 + 1], a1);
}

// ---------------- K7a: g[b,d] = (1/S) sum_t w[b,t] * xb[b,t,d] ----------------
__global__ __launch_bounds__(256) void k_accx(const float* __restrict__ w,
                                              const unsigned short* __restrict__ xb,
                                              float* __restrict__ g) {
    int b = blockIdx.z;
    int d = blockIdx.x * 256 + threadIdx.x;
    int t0 = blockIdx.y * 256;
    const unsigned short* xbb = xb + (size_t)b * SEQ * DIM;
    const float* wb = w + b * SEQ;
    float acc = 0.f;
    for (int t = t0; t < t0 + 256; ++t)
        acc += wb[t] * bf2f(xbb[(size_t)t * DIM + d]);
    atomicAdd(&g[b * DIM + d], acc * (1.0f / (float)SEQ));
}

// ---------------- K7b-init: out[b,n] = bv[n] ----------------
__global__ __launch_bounds__(256) void k_init_out(const float* __restrict__ bv,
                                                  float* __restrict__ out) {
    int i = blockIdx.x * 256 + threadIdx.x;
    out[i] = bv[i & (DIM - 1)];
}

// ---------------- K7b: out[b,n] += sum_{d in chunk} g[b,d] * Wv[d,n] ----------------
__global__ __launch_bounds__(256) void k_out2(const float* __restrict__ g,
                                              const float* __restrict__ Wv,
                                              float* __restrict__ out) {
    int b = blockIdx.y;
    int n = blockIdx.x * 256 + threadIdx.x;
    int d0 = blockIdx.z * 64;
    const float* gb = g + b * DIM;
    float acc = 0.f;
#pragma unroll
    for (int d = 0; d < 64; ++d)
        acc += gb[d0 + d] * Wv[(size_t)(d0 + d) * DIM + n];
    atomicAdd(&out[b * DIM + n], acc);
}

extern "C" void kernel_launch(void* const* d_in, const int* in_sizes, int n_in,
                              void* d_out, int out_size, void* d_ws, size_t ws_size,
                              hipStream_t stream) {
    const float* x  = (const float*)d_in[0];
    const float* Wq = (const float*)d_in[1];
    const float* bq = (const float*)d_in[2];
    const float* Wk = (const float*)d_in[3];
    const float* bk = (const float*)d_in[4];   // unused (softmax-invariant terms dropped)
    const float* Wv = (const float*)d_in[5];
    const float* bv = (const float*)d_in[6];
    float* out = (float*)d_out;
    (void)bk;

    char* ws = (char*)d_ws;
    unsigned short* xb  = (unsigned short*)(ws);                    // 33,554,432
    unsigned short* wt  = (unsigned short*)(ws + 33554432ull);      //  4,194,304 (Wq^T, Wk^T)
    unsigned short* qkv = (unsigned short*)(ws + 37748736ull);      // 67,108,864 (q0, k0)
    unsigned short* P   = (unsigned short*)(ws + 104857600ull);     // 67,108,864
    float*          ell = (float*)(ws + 171966464ull);              //     65,536
    float*          w   = (float*)(ws + 172032000ull);              //     65,536
    float*          c   = (float*)(ws + 172097536ull);              //     65,536
    float*          g   = (float*)(ws + 172163072ull);              //     32,768

    hipMemsetAsync(ell, 0, SEQ * NB * sizeof(float), stream);
    hipMemsetAsync(w,   0, SEQ * NB * sizeof(float), stream);
    hipMemsetAsync(c,   0, MTOT * sizeof(float), stream);
    hipMemsetAsync(g,   0, DIM * NB * sizeof(float), stream);

    k_cvt_x<<<dim3(MTOT * DIM / 4 / 256), 256, 0, stream>>>(x, xb);
    k_transpose_w<<<dim3(16, 16, 2), 256, 0, stream>>>(Wq, Wk, wt);
    k_proj<<<dim3(512), 512, 0, stream>>>(xb, wt, bq, qkv, c);
    k_scores<<<dim3(512), 512, 0, stream>>>(qkv, c, P, ell);
    k_recip<<<dim3(SEQ * NB / 256), 256, 0, stream>>>(ell);
    k_colsum<<<dim3(SEQ / 512, SEQ / 256, NB), 256, 0, stream>>>(P, ell, w);
    k_accx<<<dim3(DIM / 256, SEQ / 256, NB), 256, 0, stream>>>(w, xb, g);
    k_init_out<<<dim3(NB * DIM / 256), 256, 0, stream>>>(bv, out);
    k_out2<<<dim3(DIM / 256, NB, 16), 256, 0, stream>>>(g, Wv, out);
}

// Round 8
// 225.819 us; speedup vs baseline: 1.0275x; 1.0275x over previous
//
#include <hip/hip_runtime.h>

// ---------------------------------------------------------------------------
// AttentionFuse: out[b,d] = mean_s( softmax((x Wq + bq)(x Wk + bk)^T / 32) @ (x Wv + bv) )
// Algebra (R8):
//   mean_s(attn @ V) = sum_t a[t] V[t,:]  =>  out = (a^T x) Wv + bv   (V GEMM gone)
//   S = q0 k0^T = x (Wq Wk^T) x^T  =>  y = x Mt^T with Mt = Wk Wq^T (2.1 GF!)
//     => S = y x^T : K-projection GEMM eliminated entirely (k0 == x).
//   bias: P[s,t] = exp(scale*S + c[t]),  c[t] = scale * x[t].u,  u = Wk bq
//   (row-const terms dropped: softmax-invariant.)
// GEMM core: R5's best-measured variant (1 barrier/phase, frag prefetch).
// ---------------------------------------------------------------------------

using bf16x8 = __attribute__((ext_vector_type(8))) __bf16;
using u16x8  = __attribute__((ext_vector_type(8))) unsigned short;
using f32x4  = __attribute__((ext_vector_type(4))) float;

#define NB 8
#define SEQ 2048
#define DIM 1024
#define MTOT (NB * SEQ)          // 16384

__device__ __forceinline__ unsigned short f2bf(float f) {
    unsigned int u = __float_as_uint(f);
    u = u + 0x7FFFu + ((u >> 16) & 1u);   // round-to-nearest-even
    return (unsigned short)(u >> 16);
}
__device__ __forceinline__ float bf2f(unsigned short h) {
    return __uint_as_float(((unsigned int)h) << 16);
}

__device__ __forceinline__ void async16(const unsigned short* g, unsigned short* l) {
    __builtin_amdgcn_global_load_lds(
        (const __attribute__((address_space(1))) void*)g,
        (__attribute__((address_space(3))) void*)l, 16, 0, 0);
}

// ---------------- K1: x fp32 -> bf16 ----------------
__global__ __launch_bounds__(256) void k_cvt_x(const float* __restrict__ x,
                                               unsigned short* __restrict__ xb) {
    size_t i = ((size_t)blockIdx.x * 256 + threadIdx.x) * 4;
    float4 v = *reinterpret_cast<const float4*>(x + i);
    ushort4 o;
    o.x = f2bf(v.x); o.y = f2bf(v.y); o.z = f2bf(v.z); o.w = f2bf(v.w);
    *reinterpret_cast<ushort4*>(xb + i) = o;
}

// ---------------- K2: Wk,Wq fp32 -> bf16 (no transpose needed) ----------------
__global__ __launch_bounds__(256) void k_cvt_w(const float* __restrict__ Wk,
                                               const float* __restrict__ Wq,
                                               unsigned short* __restrict__ wkb,
                                               unsigned short* __restrict__ wqb) {
    const float* src = blockIdx.y ? Wq : Wk;
    unsigned short* dst = blockIdx.y ? wqb : wkb;
    size_t i = ((size_t)blockIdx.x * 256 + threadIdx.x) * 4;
    float4 v = *reinterpret_cast<const float4*>(src + i);
    ushort4 o;
    o.x = f2bf(v.x); o.y = f2bf(v.y); o.z = f2bf(v.z); o.w = f2bf(v.w);
    *reinterpret_cast<ushort4*>(dst + i) = o;
}

// ---------------- K2b: u[i] = sum_j Wk[i,j] * bq[j]  (fp32) ----------------
__global__ __launch_bounds__(256) void k_u(const float* __restrict__ Wk,
                                           const float* __restrict__ bq,
                                           float* __restrict__ u) {
    const int wave = threadIdx.x >> 6, lane = threadIdx.x & 63;
    const int row = blockIdx.x * 4 + wave;
    const float* wr = Wk + (size_t)row * DIM;
    float s = 0.f;
#pragma unroll
    for (int p = 0; p < 4; ++p) {
        int col = p * 256 + lane * 4;
        float4 v = *reinterpret_cast<const float4*>(wr + col);
        float4 b = *reinterpret_cast<const float4*>(bq + col);
        s += v.x * b.x + v.y * b.y + v.z * b.z + v.w * b.w;
    }
#pragma unroll
    for (int off = 32; off; off >>= 1) s += __shfl_xor(s, off);
    if (lane == 0) u[row] = s;
}

// ---------------- K2c: c[t] = scale * sum_i xb[t,i] * u[i] ----------------
__global__ __launch_bounds__(256) void k_c(const unsigned short* __restrict__ xb,
                                           const float* __restrict__ u,
                                           float* __restrict__ c) {
    const int wave = threadIdx.x >> 6, lane = threadIdx.x & 63;
    const int row0 = blockIdx.x * 32 + wave * 8;
    float uv[16];
#pragma unroll
    for (int j = 0; j < 16; ++j) uv[j] = u[lane * 16 + j];
    for (int i = 0; i < 8; ++i) {
        const int row = row0 + i;
        const unsigned short* xr = xb + (size_t)row * DIM + lane * 16;
        float s = 0.f;
#pragma unroll
        for (int h = 0; h < 2; ++h) {
            u16x8 kv = *reinterpret_cast<const u16x8*>(xr + h * 8);
#pragma unroll
            for (int j = 0; j < 8; ++j) s += uv[h * 8 + j] * bf2f(kv[j]);
        }
#pragma unroll
        for (int off = 32; off; off >>= 1) s += __shfl_xor(s, off);
        if (lane == 0) c[row] = 0.03125f * s;
    }
}

// ---------------- 128x128 tile GEMM (for the tiny Mt = Wk Wq^T) ----------------
__device__ __forceinline__ void gemm_bt_tile128(const unsigned short* __restrict__ A,
                                                const unsigned short* __restrict__ Bt,
                                                int K, int m0, int n0, int lda, int ldb,
                                                unsigned short* ldsA, unsigned short* ldsB,
                                                f32x4 acc[4][4]) {
    const int tid  = threadIdx.x;
    const int wave = tid >> 6;
    const int lane = tid & 63;
    const int lrow = lane >> 3;
    const int lcol = lane & 7;
    const int wm = (wave >> 1) * 64;
    const int wn = (wave & 1) * 64;
    const int fr = lane & 15;
    const int fg = lane >> 4;

    for (int k0 = 0; k0 < K; k0 += 64) {
#pragma unroll
        for (int r = 0; r < 4; ++r) {
            int row = r * 32 + wave * 8 + lrow;
            async16(A + (size_t)(m0 + row) * lda + k0 + lcol * 8, ldsA + r * 2048 + wave * 512);
            async16(Bt + (size_t)(n0 + row) * ldb + k0 + lcol * 8, ldsB + r * 2048 + wave * 512);
        }
        __syncthreads();
#pragma unroll
        for (int ks = 0; ks < 2; ++ks) {
            bf16x8 af[4], bfr[4];
#pragma unroll
            for (int mf = 0; mf < 4; ++mf)
                af[mf] = *reinterpret_cast<const bf16x8*>(ldsA + (wm + mf * 16 + fr) * 64 + ks * 32 + fg * 8);
#pragma unroll
            for (int nf = 0; nf < 4; ++nf)
                bfr[nf] = *reinterpret_cast<const bf16x8*>(ldsB + (wn + nf * 16 + fr) * 64 + ks * 32 + fg * 8);
#pragma unroll
            for (int mf = 0; mf < 4; ++mf)
#pragma unroll
                for (int nf = 0; nf < 4; ++nf)
                    acc[mf][nf] = __builtin_amdgcn_mfma_f32_16x16x32_bf16(af[mf], bfr[nf], acc[mf][nf], 0, 0, 0);
        }
        __syncthreads();
    }
}

// ---------------- K3: Mt = Wk @ Wq^T (bf16, [i'][i]) ----------------
__global__ __launch_bounds__(256) void k_mm(const unsigned short* __restrict__ wkb,
                                            const unsigned short* __restrict__ wqb,
                                            unsigned short* __restrict__ Mt) {
    __shared__ unsigned short ldsA[128 * 64];
    __shared__ unsigned short ldsB[128 * 64];
    int m0 = blockIdx.x * 128, n0 = blockIdx.y * 128;
    f32x4 acc[4][4] = {};
    gemm_bt_tile128(wkb, wqb, DIM, m0, n0, DIM, DIM, ldsA, ldsB, acc);
    const int lane = threadIdx.x & 63, wave = threadIdx.x >> 6;
    const int wm = (wave >> 1) * 64, wn = (wave & 1) * 64;
    const int fr = lane & 15, fg = lane >> 4;
#pragma unroll
    for (int nf = 0; nf < 4; ++nf) {
        int n = n0 + wn + nf * 16 + fr;
#pragma unroll
        for (int mf = 0; mf < 4; ++mf) {
            int r0 = m0 + wm + mf * 16 + fg * 4;
#pragma unroll
            for (int j = 0; j < 4; ++j)
                Mt[(size_t)(r0 + j) * DIM + n] = f2bf(acc[mf][nf][j]);
        }
    }
}

// ---------------------------------------------------------------------------
// 256x256 GEMM core (R5 best-measured variant). K = 1024.
// LDS[r][s16] = G[r][s16 ^ (r&7)]; FRAG XORs back. 1 barrier/phase.
// ---------------------------------------------------------------------------

#define STAGE(gbase, ld, dstoff)                                          \
    do {                                                                  \
        async16((gbase), ldsw + (dstoff));                                \
        async16((gbase) + 8 * (size_t)(ld), ldsw + (dstoff) + 512);       \
    } while (0)
#define STAGE_A(buf, half, kt) STAGE(gA + (size_t)((half) * 128) * lda + (kt) * 64, lda, (buf) * 16384 + (half) * 8192)
#define STAGE_B(buf, half, kt) STAGE(gB + (size_t)((half) * 128) * ldb + (kt) * 64, ldb, 32768 + (buf) * 16384 + (half) * 8192)

#define FRAG(base_us, row, colb) \
    (*(const bf16x8*)((const char*)(lds + (base_us)) + (row) * 128 + ((colb) ^ (((row) & 7) << 4))))

#define READ_A(dbuf, mh)                                                      \
    _Pragma("unroll") for (int m2 = 0; m2 < 4; ++m2) {                        \
        int arow = ((mh) * 4 + m2) * 16 + fr;                                 \
        _Pragma("unroll") for (int ks = 0; ks < 2; ++ks)                      \
            afc[(mh) * 4 + m2][ks] =                                          \
                FRAG((dbuf) * 16384 + wr * 8192, arow, ks * 64 + fg * 16);    \
    }
#define READ_B(dbuf, nh)                                                      \
    _Pragma("unroll") for (int n2 = 0; n2 < 2; ++n2) {                        \
        int brow = (wc & 1) * 64 + ((nh) * 2 + n2) * 16 + fr;                 \
        _Pragma("unroll") for (int ks = 0; ks < 2; ++ks)                      \
            bfc[nh][n2][ks] =                                                 \
                FRAG(32768 + (dbuf) * 16384 + (wc >> 1) * 8192, brow,         \
                     ks * 64 + fg * 16);                                      \
    }

#define VM4 asm volatile("s_waitcnt vmcnt(4)" ::: "memory")

#define PHASE(mh, nh, STG, VM, PF)                                            \
    do {                                                                      \
        STG;                                                                  \
        VM;                                                                   \
        asm volatile("s_barrier" ::: "memory");                               \
        asm volatile("s_waitcnt lgkmcnt(0)" ::: "memory");                    \
        __builtin_amdgcn_sched_barrier(0);                                    \
        PF;                                                                   \
        __builtin_amdgcn_sched_barrier(0);                                    \
        __builtin_amdgcn_s_setprio(1);                                        \
        _Pragma("unroll") for (int m2 = 0; m2 < 4; ++m2)                      \
            _Pragma("unroll") for (int n2 = 0; n2 < 2; ++n2) {                \
                f32x4& a = acc[(mh) * 4 + m2][(nh) * 2 + n2];                 \
                a = __builtin_amdgcn_mfma_f32_16x16x32_bf16(                  \
                    afc[(mh) * 4 + m2][0], bfc[nh][n2][0], a, 0, 0, 0);       \
                a = __builtin_amdgcn_mfma_f32_16x16x32_bf16(                  \
                    afc[(mh) * 4 + m2][1], bfc[nh][n2][1], a, 0, 0, 0);       \
            }                                                                 \
        __builtin_amdgcn_s_setprio(0);                                        \
    } while (0)

__device__ __forceinline__ void gemm256(const unsigned short* __restrict__ A,
                                        const unsigned short* __restrict__ Bt,
                                        int lda, int ldb, int m0, int n0,
                                        unsigned short* lds, f32x4 (&acc)[8][4]) {
    constexpr int NKT = 1024 / 64;   // 16 K-tiles
    constexpr int NIT = NKT / 2;     // 8 iterations
    const int tid = threadIdx.x;
    const int w = tid >> 6, lane = tid & 63;
    const int wr = w >> 2, wc = w & 3;
    const int fr = lane & 15, fg = lane >> 4;
    const int r8 = lane >> 3, slot = (lane & 7) ^ r8;

    const unsigned short* gA = A + (size_t)(m0 + w * 16 + r8) * lda + slot * 8;
    const unsigned short* gB = Bt + (size_t)(n0 + w * 16 + r8) * ldb + slot * 8;
    unsigned short* ldsw = lds + w * 1024;

    bf16x8 afc[8][2];
    bf16x8 bfc[2][2][2];

    STAGE_A(0, 0, 0); STAGE_A(0, 1, 0); STAGE_B(0, 0, 0); STAGE_B(0, 1, 0);
    STAGE_A(1, 0, 1); STAGE_A(1, 1, 1);
    VM4;
    asm volatile("s_barrier" ::: "memory");
    READ_A(0, 0); READ_B(0, 0);

    for (int it = 0; it < NIT; ++it) {
        const int t1 = 2 * it + 1;
        const int ka = (2 * it + 2) & (NKT - 1);
        const int kb = (2 * it + 3) & (NKT - 1);
        PHASE(0, 0, STAGE_B(1, 0, t1), , READ_A(0, 1));
        PHASE(1, 0, STAGE_B(1, 1, t1), , READ_B(0, 1));
        PHASE(0, 1, STAGE_A(0, 0, ka), , );
        PHASE(1, 1, STAGE_A(0, 1, ka), VM4, READ_A(1, 0); READ_B(1, 0));
        PHASE(0, 0, STAGE_B(0, 0, ka), , READ_A(1, 1));
        PHASE(1, 0, STAGE_B(0, 1, ka), , READ_B(1, 1));
        PHASE(0, 1, STAGE_A(1, 0, kb), , );
        PHASE(1, 1, STAGE_A(1, 1, kb), VM4, READ_A(0, 0); READ_B(0, 0));
    }
    asm volatile("s_waitcnt vmcnt(0) lgkmcnt(0)" ::: "memory");
}

// ---------------- K4: y = xb @ Mt^T (bf16) ----------------
__global__ __launch_bounds__(512, 2) void k_proj_y(const unsigned short* __restrict__ xb,
                                                   const unsigned short* __restrict__ Mt,
                                                   unsigned short* __restrict__ y) {
    __shared__ unsigned short lds[65536];   // 128 KiB
    // XCD swizzle: xcd = f&7 owns contiguous 8-m-tile chunk
    const int f = blockIdx.x;
    const int m_hi = f & 7, j = f >> 3;
    const int n_t = j & 3, m_lo = j >> 2;
    const int m0 = (m_hi * 8 + m_lo) * 256, n0 = n_t * 256;

    f32x4 acc[8][4] = {};
    gemm256(xb, Mt, DIM, DIM, m0, n0, lds, acc);

    const int tid = threadIdx.x, w = tid >> 6, lane = tid & 63;
    const int wr = w >> 2, wc = w & 3, fr = lane & 15, fg = lane >> 4;
#pragma unroll
    for (int nf = 0; nf < 4; ++nf) {
        int n = n0 + wc * 64 + nf * 16 + fr;
#pragma unroll
        for (int mf = 0; mf < 8; ++mf) {
            int r0 = m0 + wr * 128 + mf * 16 + fg * 4;
#pragma unroll
            for (int j2 = 0; j2 < 4; ++j2)
                y[(size_t)(r0 + j2) * DIM + n] = f2bf(acc[mf][nf][j2]);
        }
    }
}

// ---------------- K5: P = exp(y x^T * scale + c[t]) bf16, ell = rowsum ----------------
__global__ __launch_bounds__(512, 2) void k_scores(const unsigned short* __restrict__ y,
                                                   const unsigned short* __restrict__ xb,
                                                   const float* __restrict__ c,
                                                   unsigned short* __restrict__ P,
                                                   float* __restrict__ ell) {
    __shared__ unsigned short lds[65536];
    const int f = blockIdx.x;
    const int b = f & 7, j = f >> 3;
    const int mt = j & 7, nt = j >> 3;
    const unsigned short* q = y + (size_t)b * SEQ * DIM;
    const unsigned short* k = xb + (size_t)b * SEQ * DIM;
    const int m0 = mt * 256, n0 = nt * 256;

    f32x4 acc[8][4] = {};
    gemm256(q, k, DIM, DIM, m0, n0, lds, acc);

    const float scale = 0.03125f;  // 1/sqrt(1024)
    const int tid = threadIdx.x, w = tid >> 6, lane = tid & 63;
    const int wr = w >> 2, wc = w & 3, fr = lane & 15, fg = lane >> 4;
    unsigned short* Pb = P + (size_t)b * SEQ * SEQ;
    float cv[4];
#pragma unroll
    for (int nf = 0; nf < 4; ++nf)
        cv[nf] = c[(size_t)b * SEQ + n0 + wc * 64 + nf * 16 + fr];
#pragma unroll
    for (int mf = 0; mf < 8; ++mf) {
#pragma unroll
        for (int j2 = 0; j2 < 4; ++j2) {
            int s = m0 + wr * 128 + mf * 16 + fg * 4 + j2;
            float rs = 0.f;
#pragma unroll
            for (int nf = 0; nf < 4; ++nf) {
                int t = n0 + wc * 64 + nf * 16 + fr;
                float p = __expf(acc[mf][nf][j2] * scale + cv[nf]);
                unsigned short pu = f2bf(p);
                Pb[(size_t)s * SEQ + t] = pu;
                rs += bf2f(pu);
            }
            rs += __shfl_xor(rs, 1);
            rs += __shfl_xor(rs, 2);
            rs += __shfl_xor(rs, 4);
            rs += __shfl_xor(rs, 8);
            if (fr == 0) atomicAdd(&ell[b * SEQ + s], rs);
        }
    }
}

// ---------------- K6: w[b,t] = sum_s P[b,s,t] / ell[b,s]  (8 cols/thread) ----------------
__global__ __launch_bounds__(256) void k_colsum(const unsigned short* __restrict__ P,
                                                const float* __restrict__ ell,
                                                float* __restrict__ w) {
    int b = blockIdx.z;
    int t8 = threadIdx.x * 8;
    int s0 = blockIdx.y * 64;
    const unsigned short* Pb = P + (size_t)b * SEQ * SEQ;
    const float* eb = ell + b * SEQ;
    float a[8] = {};
    for (int s = s0; s < s0 + 64; ++s) {
        u16x8 pv = *reinterpret_cast<const u16x8*>(Pb + (size_t)s * SEQ + t8);
        float re = 1.0f / eb[s];
#pragma unroll
        for (int j = 0; j < 8; ++j) a[j] += bf2f(pv[j]) * re;
    }
#pragma unroll
    for (int j = 0; j < 8; ++j) atomicAdd(&w[b * SEQ + t8 + j], a[j]);
}

// ---------------- K7a: g[b,d] = (1/S) sum_t w[b,t] * xb[b,t,d] ----------------
__global__ __launch_bounds__(256) void k_accx(const float* __restrict__ w,
                                              const unsigned short* __restrict__ xb,
                                              float* __restrict__ g) {
    int b = blockIdx.z;
    int d = blockIdx.x * 256 + threadIdx.x;
    int t0 = blockIdx.y * 256;
    const unsigned short* xbb = xb + (size_t)b * SEQ * DIM;
    const float* wb = w + b * SEQ;
    float acc = 0.f;
    for (int t = t0; t < t0 + 256; ++t)
        acc += wb[t] * bf2f(xbb[(size_t)t * DIM + d]);
    atomicAdd(&g[b * DIM + d], acc * (1.0f / (float)SEQ));
}

// ---------------- K7b-init: out[b,n] = bv[n] ----------------
__global__ __launch_bounds__(256) void k_init_out(const float* __restrict__ bv,
                                                  float* __restrict__ out) {
    int i = blockIdx.x * 256 + threadIdx.x;
    out[i] = bv[i & (DIM - 1)];
}

// ---------------- K7b: out[b,n] += sum_{d in chunk} g[b,d] * Wv[d,n] ----------------
__global__ __launch_bounds__(256) void k_out2(const float* __restrict__ g,
                                              const float* __restrict__ Wv,
                                              float* __restrict__ out) {
    int b = blockIdx.y;
    int n = blockIdx.x * 256 + threadIdx.x;
    int d0 = blockIdx.z * 64;
    const float* gb = g + b * DIM;
    float acc = 0.f;
#pragma unroll
    for (int d = 0; d < 64; ++d)
        acc += gb[d0 + d] * Wv[(size_t)(d0 + d) * DIM + n];
    atomicAdd(&out[b * DIM + n], acc);
}

extern "C" void kernel_launch(void* const* d_in, const int* in_sizes, int n_in,
                              void* d_out, int out_size, void* d_ws, size_t ws_size,
                              hipStream_t stream) {
    const float* x  = (const float*)d_in[0];
    const float* Wq = (const float*)d_in[1];
    const float* bq = (const float*)d_in[2];
    const float* Wk = (const float*)d_in[3];
    const float* bk = (const float*)d_in[4];   // unused (softmax-invariant)
    const float* Wv = (const float*)d_in[5];
    const float* bv = (const float*)d_in[6];
    float* out = (float*)d_out;
    (void)bk;

    char* ws = (char*)d_ws;
    unsigned short* xb  = (unsigned short*)(ws);                    //  33,554,432
    unsigned short* wkb = (unsigned short*)(ws + 33554432ull);      //   2,097,152
    unsigned short* wqb = (unsigned short*)(ws + 35651584ull);      //   2,097,152
    unsigned short* Mt  = (unsigned short*)(ws + 37748736ull);      //   2,097,152
    unsigned short* y   = (unsigned short*)(ws + 39845888ull);      //  33,554,432
    unsigned short* P   = (unsigned short*)(ws + 73400320ull);      //  67,108,864
    float*          ell = (float*)(ws + 140509184ull);              //      65,536
    float*          w   = (float*)(ws + 140574720ull);              //      65,536
    float*          c   = (float*)(ws + 140640256ull);              //      65,536
    float*          u   = (float*)(ws + 140705792ull);              //       4,096
    float*          g   = (float*)(ws + 140709888ull);              //      32,768

    hipMemsetAsync(ell, 0, SEQ * NB * sizeof(float), stream);
    hipMemsetAsync(w,   0, SEQ * NB * sizeof(float), stream);
    hipMemsetAsync(g,   0, DIM * NB * sizeof(float), stream);

    k_cvt_w<<<dim3(DIM * DIM / 4 / 256, 2), 256, 0, stream>>>(Wk, Wq, wkb, wqb);
    k_cvt_x<<<dim3(MTOT * DIM / 4 / 256), 256, 0, stream>>>(x, xb);
    k_u<<<dim3(DIM / 4), 256, 0, stream>>>(Wk, bq, u);
    k_mm<<<dim3(8, 8), 256, 0, stream>>>(wkb, wqb, Mt);
    k_c<<<dim3(MTOT / 32), 256, 0, stream>>>(xb, u, c);
    k_proj_y<<<dim3(256), 512, 0, stream>>>(xb, Mt, y);
    k_scores<<<dim3(512), 512, 0, stream>>>(y, xb, c, P, ell);
    k_colsum<<<dim3(1, SEQ / 64, NB), 256, 0, stream>>>(P, ell, w);
    k_accx<<<dim3(DIM / 256, SEQ / 256, NB), 256, 0, stream>>>(w, xb, g);
    k_init_out<<<dim3(NB * DIM / 256), 256, 0, stream>>>(bv, out);
    k_out2<<<dim3(DIM / 256, NB, 16), 256, 0, stream>>>(g, Wv, out);
}